// Round 1
// baseline (547.805 us; speedup 1.0000x reference)
//
#include <hip/hip_runtime.h>
#include <hip/hip_bf16.h>

// ---------------------------------------------------------------------------
// EncoderLayer on MI355X (gfx950), bf16 MFMA pipeline.
//   x[4,2048,1024] -> QKV proj -> MHA (flash, online softmax) -> Wc+bias+res
//   -> RMSNorm -> gated MLP (silu(h@L1^T)*(h@L2^T))@L3^T + res -> RMSNorm
// ---------------------------------------------------------------------------

#define EMB   1024
#define HEADS 16
#define DK    64
#define INNER 2816
#define BATCH 4
#define NTOK  2048
#define MROWS (BATCH * NTOK)   // 8192

typedef short bf16x8 __attribute__((ext_vector_type(8)));
typedef short s16x4  __attribute__((ext_vector_type(4)));
typedef float f32x4  __attribute__((ext_vector_type(4)));

typedef const void __attribute__((address_space(1)))* gas_cvp;
typedef void       __attribute__((address_space(3)))* las_vp;

__device__ __forceinline__ short to_bf16(float f) {
  union { float f; unsigned u; } x; x.f = f;
  unsigned r = x.u + 0x7FFFu + ((x.u >> 16) & 1u);   // RNE
  return (short)(r >> 16);
}

// async global->LDS, 16B per lane; LDS dest must be linear (base + lane*16)
__device__ __forceinline__ void gld16(void* lds, const void* g) {
  __builtin_amdgcn_global_load_lds((gas_cvp)g, (las_vp)lds, 16, 0, 0);
}

// ---------------------------------------------------------------------------
// f32 -> bf16 conversion (vectorized)
// ---------------------------------------------------------------------------
__global__ __launch_bounds__(256, 4)
void cvtk(const float* __restrict__ s, short* __restrict__ d, int n4) {
  int i = blockIdx.x * 256 + threadIdx.x;
  if (i < n4) {
    float4 v = ((const float4*)s)[i];
    s16x4 o;
    o[0] = to_bf16(v.x); o[1] = to_bf16(v.y);
    o[2] = to_bf16(v.z); o[3] = to_bf16(v.w);
    ((s16x4*)d)[i] = o;
  }
}

// interleave L1/L2 rows: dst[2n]=L1[n], dst[2n+1]=L2[n]   (rows of 1024)
__global__ __launch_bounds__(256, 4)
void cvt_inter(const float* __restrict__ L1, const float* __restrict__ L2,
               short* __restrict__ d) {
  int i = blockIdx.x * 256 + threadIdx.x;      // over 2816*256 float4 slots
  if (i >= INNER * 256) return;
  int row = i >> 8, c4 = i & 255;
  float4 v1 = ((const float4*)L1)[i];
  float4 v2 = ((const float4*)L2)[i];
  s16x4 o1, o2;
  o1[0]=to_bf16(v1.x); o1[1]=to_bf16(v1.y); o1[2]=to_bf16(v1.z); o1[3]=to_bf16(v1.w);
  o2[0]=to_bf16(v2.x); o2[1]=to_bf16(v2.y); o2[2]=to_bf16(v2.z); o2[3]=to_bf16(v2.w);
  ((s16x4*)d)[(size_t)(2 * row) * 256 + c4]     = o1;
  ((s16x4*)d)[(size_t)(2 * row + 1) * 256 + c4] = o2;
}

// ---------------------------------------------------------------------------
// GEMM  C[M,N] = A[M,K] @ B[N,K]^T   (bf16 in, fp32 acc), 128x128 tile, BK=64
// MODE 0: QKV  -> out0=q[std], out1=k[std], out2=v transposed [b,h,d,tok]
// MODE 1: Wc   -> out0 = acc + bc[n] + x[m,n]  (fp32)
// MODE 2: MLP12 (interleaved cols u,g) -> out0 = bf16(silu(u)*g), N/2 cols
// MODE 3: L3   -> out0 = acc + h32[m,n]  (fp32)
// ---------------------------------------------------------------------------
template<int MODE>
__global__ __launch_bounds__(256, 2)
void gemm_bt(const short* __restrict__ A, const short* __restrict__ Bw,
             int M, int N, int K,
             void* __restrict__ out0, void* __restrict__ out1,
             void* __restrict__ out2,
             const float* __restrict__ aux0, const float* __restrict__ aux1)
{
  __shared__ short At[128 * 64];
  __shared__ short Bt[128 * 64];
  const int t = threadIdx.x;
  const int lane = t & 63;
  const int l15 = lane & 15, lhi = lane >> 4;
  const int w  = t >> 6;
  const int wm = (w >> 1) << 6;        // wave row offset (0/64)
  const int wn = (w & 1) << 6;         // wave col offset (0/64)
  const int tilesN = N >> 7;
  const int m0 = (blockIdx.x / tilesN) << 7;
  const int n0 = (blockIdx.x % tilesN) << 7;

  // staging: thread t loads row r=t>>3, 16B piece p=t&7; source piece is
  // pre-swizzled (p ^ (r&7)) so that swizzled ds_reads see the right data.
  const int r = t >> 3;
  const int p = t & 7;
  const int psrc = p ^ (r & 7);
  const short* Ag = A  + (size_t)(m0 + r) * K + psrc * 8;
  const short* Bg = Bw + (size_t)(n0 + r) * K + psrc * 8;

  f32x4 acc[4][4];
  const f32x4 fz = {0.f, 0.f, 0.f, 0.f};
#pragma unroll
  for (int i = 0; i < 4; i++)
#pragma unroll
    for (int j = 0; j < 4; j++) acc[i][j] = fz;

  int aoff[2][4], boff[2][4];
#pragma unroll
  for (int kk = 0; kk < 2; kk++)
#pragma unroll
    for (int mt = 0; mt < 4; mt++) {
      int ra = wm + mt * 16 + l15;
      aoff[kk][mt] = ra * 128 + ((kk * 64 + lhi * 16) ^ ((ra & 7) << 4));
      int rb = wn + mt * 16 + l15;
      boff[kk][mt] = rb * 128 + ((kk * 64 + lhi * 16) ^ ((rb & 7) << 4));
    }

  for (int k0 = 0; k0 < K; k0 += 64) {
#pragma unroll
    for (int i = 0; i < 4; i++) {
      gld16((char*)At + t * 16 + i * 4096, Ag + (size_t)i * 32 * K + k0);
      gld16((char*)Bt + t * 16 + i * 4096, Bg + (size_t)i * 32 * K + k0);
    }
    __syncthreads();                       // drains vmcnt, tile visible
#pragma unroll
    for (int kk = 0; kk < 2; kk++) {
      bf16x8 a[4], b[4];
#pragma unroll
      for (int mt = 0; mt < 4; mt++)
        a[mt] = *(const bf16x8*)((const char*)At + aoff[kk][mt]);
#pragma unroll
      for (int nt = 0; nt < 4; nt++)
        b[nt] = *(const bf16x8*)((const char*)Bt + boff[kk][nt]);
#pragma unroll
      for (int mt = 0; mt < 4; mt++)
#pragma unroll
        for (int nt = 0; nt < 4; nt++)
          acc[mt][nt] = __builtin_amdgcn_mfma_f32_16x16x32_bf16(
              a[mt], b[nt], acc[mt][nt], 0, 0, 0);
    }
    __syncthreads();                       // protect tile before restage
  }

  // epilogue: element (lane,j) of acc[mt][nt] is C[mb+j][n],
  //   mb = m0+wm+mt*16+lhi*4, n = n0+wn+nt*16+l15
#pragma unroll
  for (int mt = 0; mt < 4; mt++) {
#pragma unroll
    for (int nt = 0; nt < 4; nt++) {
      const int mb = m0 + wm + mt * 16 + lhi * 4;
      const int n  = n0 + wn + nt * 16 + l15;
      if constexpr (MODE == 0) {
        const int which = n >> 10, c = n & 1023;
        if (which == 2) {                  // V: [b,h,d,tok] transposed
          const int hh = c >> 6, dd = c & 63;
          const int bb = mb >> 11, tok = mb & 2047;
          s16x4 pk;
#pragma unroll
          for (int j = 0; j < 4; j++) pk[j] = to_bf16(acc[mt][nt][j]);
          *(s16x4*)((short*)out2 +
                    (size_t)((bb * HEADS + hh) * DK + dd) * NTOK + tok) = pk;
        } else {
          short* dst = (which == 0) ? (short*)out0 : (short*)out1;
#pragma unroll
          for (int j = 0; j < 4; j++)
            dst[(size_t)(mb + j) * 1024 + c] = to_bf16(acc[mt][nt][j]);
        }
      } else if constexpr (MODE == 1) {
#pragma unroll
        for (int j = 0; j < 4; j++) {
          size_t idx = (size_t)(mb + j) * 1024 + n;
          ((float*)out0)[idx] = acc[mt][nt][j] + aux1[n] + aux0[idx];
        }
      } else if constexpr (MODE == 2) {
#pragma unroll
        for (int j = 0; j < 4; j++) {
          float v0 = acc[mt][nt][j];
          float v1 = __shfl_xor(v0, 1);    // partner column (u<->g pair)
          if ((lane & 1) == 0) {
            float su = v0 / (1.f + __expf(-v0));   // silu(u)
            ((short*)out0)[(size_t)(mb + j) * INNER + (n >> 1)] =
                to_bf16(su * v1);
          }
        }
      } else {                             // MODE 3
#pragma unroll
        for (int j = 0; j < 4; j++) {
          size_t idx = (size_t)(mb + j) * 1024 + n;
          ((float*)out0)[idx] = acc[mt][nt][j] + aux0[idx];
        }
      }
    }
  }
}

// ---------------------------------------------------------------------------
// Flash attention: grid (64 bh, 32 qtiles), 4 waves x 16 q-rows, KV tile 64.
// q,k std layout [b,tok,h*64+d]; v transposed [b,h,d,tok]; out std layout.
// ---------------------------------------------------------------------------
__global__ __launch_bounds__(256, 2)
void attn_k(const short* __restrict__ qb, const short* __restrict__ kb,
            const short* __restrict__ vtb, short* __restrict__ ob)
{
  __shared__ short Kt[64 * 64];
  __shared__ short Vt[64 * 64];
  __shared__ short Pt[64 * 64];
  const int t = threadIdx.x;
  const int lane = t & 63;
  const int l15 = lane & 15, lhi = lane >> 4;
  const int w = t >> 6;
  const int bh = blockIdx.x;
  const int b = bh >> 4, h = bh & 15;
  const int q0 = blockIdx.y << 6;

  // Q fragments (A operand), rows q0+w*16+l15
  bf16x8 aq[2];
  {
    const short* qp = qb + (size_t)(b * NTOK + q0 + w * 16 + l15) * EMB
                         + h * DK + lhi * 8;
    aq[0] = *(const bf16x8*)qp;
    aq[1] = *(const bf16x8*)(qp + 32);
  }

  f32x4 acc_o[4];
  const f32x4 fz = {0.f, 0.f, 0.f, 0.f};
#pragma unroll
  for (int dt = 0; dt < 4; dt++) acc_o[dt] = fz;
  float m_run[4] = {-3.0e38f, -3.0e38f, -3.0e38f, -3.0e38f};
  float l_run[4] = {0.f, 0.f, 0.f, 0.f};

  const int r = t >> 3, p = t & 7;
  const int psrc = p ^ (r & 7);
  const short* kg = kb  + (size_t)(b * NTOK + r) * EMB + h * DK + psrc * 8;
  const short* vg = vtb + (size_t)(bh * DK + r) * NTOK + psrc * 8;

  int kvoff[4][2], poff[2];
#pragma unroll
  for (int nt = 0; nt < 4; nt++)
#pragma unroll
    for (int kk = 0; kk < 2; kk++) {
      int row = nt * 16 + l15;
      kvoff[nt][kk] = row * 128 + ((kk * 64 + lhi * 16) ^ ((row & 7) << 4));
    }
  {
    int row = w * 16 + l15;
#pragma unroll
    for (int kk = 0; kk < 2; kk++)
      poff[kk] = row * 128 + ((kk * 64 + lhi * 16) ^ ((row & 7) << 4));
  }

  for (int kv0 = 0; kv0 < NTOK; kv0 += 64) {
    __syncthreads();                       // previous tile fully consumed
#pragma unroll
    for (int i = 0; i < 2; i++) {
      gld16((char*)Kt + t * 16 + i * 4096, kg + (size_t)(kv0 + i * 32) * EMB);
      gld16((char*)Vt + t * 16 + i * 4096, vg + (size_t)i * 32 * NTOK + kv0);
    }
    __syncthreads();

    // S = Q @ K^T  (rows m=lhi*4+j, cols n=nt*16+l15)
    f32x4 s[4];
#pragma unroll
    for (int nt = 0; nt < 4; nt++) {
      s[nt] = fz;
#pragma unroll
      for (int kk = 0; kk < 2; kk++) {
        bf16x8 bk = *(const bf16x8*)((const char*)Kt + kvoff[nt][kk]);
        s[nt] = __builtin_amdgcn_mfma_f32_16x16x32_bf16(aq[kk], bk, s[nt], 0, 0, 0);
      }
    }
    // online softmax (wave-parallel; row spread over 16 lanes x 4 nt)
#pragma unroll
    for (int j = 0; j < 4; j++) {
#pragma unroll
      for (int nt = 0; nt < 4; nt++) s[nt][j] *= 0.125f;
      float mx = fmaxf(fmaxf(s[0][j], s[1][j]), fmaxf(s[2][j], s[3][j]));
      mx = fmaxf(mx, __shfl_xor(mx, 1));
      mx = fmaxf(mx, __shfl_xor(mx, 2));
      mx = fmaxf(mx, __shfl_xor(mx, 4));
      mx = fmaxf(mx, __shfl_xor(mx, 8));
      float mnew = fmaxf(m_run[j], mx);
      float alpha = exp2f((m_run[j] - mnew) * 1.44269504f);
      m_run[j] = mnew;
      float sum = 0.f;
#pragma unroll
      for (int nt = 0; nt < 4; nt++) {
        float pe = exp2f((s[nt][j] - mnew) * 1.44269504f);
        s[nt][j] = pe;
        sum += pe;
      }
      sum += __shfl_xor(sum, 1);
      sum += __shfl_xor(sum, 2);
      sum += __shfl_xor(sum, 4);
      sum += __shfl_xor(sum, 8);
      l_run[j] = l_run[j] * alpha + sum;
#pragma unroll
      for (int dt = 0; dt < 4; dt++) acc_o[dt][j] *= alpha;
    }
    // repack P (acc layout) -> per-wave LDS strip (A-frag layout), swizzled
#pragma unroll
    for (int nt = 0; nt < 4; nt++)
#pragma unroll
      for (int j = 0; j < 4; j++) {
        int wrow = w * 16 + lhi * 4 + j;
        int off = wrow * 128 + (((nt * 16 + l15) * 2) ^ ((wrow & 7) << 4));
        *(short*)((char*)Pt + off) = to_bf16(s[nt][j]);
      }
    // O += P @ V
    bf16x8 ap[2];
#pragma unroll
    for (int kk = 0; kk < 2; kk++)
      ap[kk] = *(const bf16x8*)((const char*)Pt + poff[kk]);
#pragma unroll
    for (int dt = 0; dt < 4; dt++)
#pragma unroll
      for (int kk = 0; kk < 2; kk++) {
        bf16x8 bv = *(const bf16x8*)((const char*)Vt + kvoff[dt][kk]);
        acc_o[dt] = __builtin_amdgcn_mfma_f32_16x16x32_bf16(ap[kk], bv, acc_o[dt], 0, 0, 0);
      }
  }

#pragma unroll
  for (int j = 0; j < 4; j++) {
    float inv = 1.f / l_run[j];
    size_t m = (size_t)(b * NTOK + q0 + w * 16 + lhi * 4 + j);
#pragma unroll
    for (int dt = 0; dt < 4; dt++)
      ob[m * EMB + h * DK + dt * 16 + l15] = to_bf16(acc_o[dt][j] * inv);
  }
}

// ---------------------------------------------------------------------------
// RMSNorm over rows of 1024 fp32. WB: also emit bf16 copy.
// ---------------------------------------------------------------------------
template<bool WB>
__global__ __launch_bounds__(256, 4)
void rmsnorm_k(const float* __restrict__ in, const float* __restrict__ gw,
               float* __restrict__ of, short* __restrict__ ob)
{
  const int row = blockIdx.x;
  const int t = threadIdx.x;
  const float4 v = ((const float4*)(in + (size_t)row * EMB))[t];
  float ss = v.x * v.x + v.y * v.y + v.z * v.z + v.w * v.w;
#pragma unroll
  for (int off = 1; off < 64; off <<= 1) ss += __shfl_xor(ss, off);
  __shared__ float red[4];
  if ((t & 63) == 0) red[t >> 6] = ss;
  __syncthreads();
  float tot = red[0] + red[1] + red[2] + red[3];
  const float rinv = rsqrtf(tot * (1.f / EMB) + 1e-6f);
  const float4 g4 = ((const float4*)gw)[t];
  float4 o;
  o.x = v.x * rinv * g4.x; o.y = v.y * rinv * g4.y;
  o.z = v.z * rinv * g4.z; o.w = v.w * rinv * g4.w;
  ((float4*)(of + (size_t)row * EMB))[t] = o;
  if (WB) {
    s16x4 pk;
    pk[0] = to_bf16(o.x); pk[1] = to_bf16(o.y);
    pk[2] = to_bf16(o.z); pk[3] = to_bf16(o.w);
    ((s16x4*)(ob + (size_t)row * EMB))[t] = pk;
  }
}

// ---------------------------------------------------------------------------
extern "C" void kernel_launch(void* const* d_in, const int* in_sizes, int n_in,
                              void* d_out, int out_size, void* d_ws, size_t ws_size,
                              hipStream_t stream)
{
  const float* x  = (const float*)d_in[0];
  const float* Wq = (const float*)d_in[1];
  const float* Wk = (const float*)d_in[2];
  const float* Wv = (const float*)d_in[3];
  const float* Wc = (const float*)d_in[4];
  const float* bc = (const float*)d_in[5];
  const float* g1 = (const float*)d_in[6];
  const float* g2 = (const float*)d_in[7];
  const float* L1 = (const float*)d_in[8];
  const float* L2 = (const float*)d_in[9];
  const float* L3 = (const float*)d_in[10];
  float* out = (float*)d_out;

  char* ws = (char*)d_ws;
  size_t o = 0;
  auto take = [&](size_t bytes) -> char* {
    char* pp = ws + o;
    o += (bytes + 255) & ~(size_t)255;
    return pp;
  };
  short* xb   = (short*)take((size_t)MROWS * EMB * 2);
  short* wqkv = (short*)take((size_t)3072 * 1024 * 2);
  short* wcb  = (short*)take((size_t)1024 * 1024 * 2);
  short* l12  = (short*)take((size_t)5632 * 1024 * 2);
  short* l3b  = (short*)take((size_t)1024 * 2816 * 2);
  short* q    = (short*)take((size_t)MROWS * EMB * 2);
  short* k    = (short*)take((size_t)MROWS * EMB * 2);
  short* v    = (short*)take((size_t)MROWS * EMB * 2);
  short* attn = (short*)take((size_t)MROWS * EMB * 2);
  float* t1   = (float*)take((size_t)MROWS * EMB * 4);
  float* h32  = (float*)take((size_t)MROWS * EMB * 4);
  short* hb   = (short*)take((size_t)MROWS * EMB * 2);
  short* gated = q;   // reuse q/k/v region (dead after attention)
  float* t2    = t1;  // reuse t1 (dead after norm1)

  // conversions
  cvtk<<<MROWS * EMB / 4 / 256, 256, 0, stream>>>(x, xb, MROWS * EMB / 4);
  cvtk<<<1024 * 1024 / 4 / 256, 256, 0, stream>>>(Wq, wqkv, 1024 * 1024 / 4);
  cvtk<<<1024 * 1024 / 4 / 256, 256, 0, stream>>>(Wk, wqkv + 1024 * 1024, 1024 * 1024 / 4);
  cvtk<<<1024 * 1024 / 4 / 256, 256, 0, stream>>>(Wv, wqkv + 2 * 1024 * 1024, 1024 * 1024 / 4);
  cvtk<<<1024 * 1024 / 4 / 256, 256, 0, stream>>>(Wc, wcb, 1024 * 1024 / 4);
  cvt_inter<<<INNER, 256, 0, stream>>>(L1, L2, l12);
  cvtk<<<1024 * 2816 / 4 / 256, 256, 0, stream>>>(L3, l3b, 1024 * 2816 / 4);

  // QKV projection (N = 3072 = q|k|v)
  gemm_bt<0><<<64 * 24, 256, 0, stream>>>(xb, wqkv, MROWS, 3072, 1024,
                                          q, k, v, nullptr, nullptr);
  // attention
  attn_k<<<dim3(64, 32), 256, 0, stream>>>(q, k, v, attn);
  // Wc projection + bias + residual -> t1 (fp32)
  gemm_bt<1><<<64 * 8, 256, 0, stream>>>(attn, wcb, MROWS, 1024, 1024,
                                         t1, nullptr, nullptr, x, bc);
  // h = rmsnorm(t1, g1): fp32 + bf16 copies
  rmsnorm_k<true><<<MROWS, 256, 0, stream>>>(t1, g1, h32, hb);
  // gated MLP up: interleaved u,g columns, fused silu-gate -> gated (bf16)
  gemm_bt<2><<<64 * 44, 256, 0, stream>>>(hb, l12, MROWS, 5632, 1024,
                                          gated, nullptr, nullptr, nullptr, nullptr);
  // down proj + residual -> t2 (fp32)
  gemm_bt<3><<<64 * 8, 256, 0, stream>>>(gated, l3b, MROWS, 1024, 2816,
                                         t2, nullptr, nullptr, h32, nullptr);
  // final norm -> d_out
  rmsnorm_k<false><<<MROWS, 256, 0, stream>>>(t2, g2, out, nullptr);
}

// Round 2
// 459.303 us; speedup vs baseline: 1.1927x; 1.1927x over previous
//
#include <hip/hip_runtime.h>
#include <hip/hip_bf16.h>

// ---------------------------------------------------------------------------
// EncoderLayer on MI355X (gfx950), bf16 MFMA pipeline.
//   x[4,2048,1024] -> QKV proj -> MHA (flash, online softmax) -> Wc+bias+res
//   -> RMSNorm -> gated MLP (silu(h@L1^T)*(h@L2^T))@L3^T + res -> RMSNorm
// ---------------------------------------------------------------------------

#define EMB   1024
#define HEADS 16
#define DK    64
#define INNER 2816
#define BATCH 4
#define NTOK  2048
#define MROWS (BATCH * NTOK)   // 8192

// q pre-scale: 1/sqrt(64) * log2(e)  (softmax done in exp2 domain)
#define QSCALE 0.18033688011112042f

typedef short bf16x8 __attribute__((ext_vector_type(8)));
typedef short s16x4  __attribute__((ext_vector_type(4)));
typedef float f32x4  __attribute__((ext_vector_type(4)));

typedef const void __attribute__((address_space(1)))* gas_cvp;
typedef void       __attribute__((address_space(3)))* las_vp;

__device__ __forceinline__ short to_bf16(float f) {
  union { float f; unsigned u; } x; x.f = f;
  unsigned r = x.u + 0x7FFFu + ((x.u >> 16) & 1u);   // RNE
  return (short)(r >> 16);
}

// packed f32x2 -> bf16x2 (low = a, high = b)
__device__ __forceinline__ unsigned cvt_pk_bf16(float a, float b) {
  unsigned r;
  asm("v_cvt_pk_bf16_f32 %0, %1, %2" : "=v"(r) : "v"(a), "v"(b));
  return r;
}

// async global->LDS, 16B per lane; LDS dest must be linear (base + lane*16)
__device__ __forceinline__ void gld16(void* lds, const void* g) {
  __builtin_amdgcn_global_load_lds((gas_cvp)g, (las_vp)lds, 16, 0, 0);
}

// ---------------------------------------------------------------------------
// f32 -> bf16 conversion (vectorized)
// ---------------------------------------------------------------------------
__global__ __launch_bounds__(256, 4)
void cvtk(const float* __restrict__ s, short* __restrict__ d, int n4) {
  int i = blockIdx.x * 256 + threadIdx.x;
  if (i < n4) {
    float4 v = ((const float4*)s)[i];
    s16x4 o;
    o[0] = to_bf16(v.x); o[1] = to_bf16(v.y);
    o[2] = to_bf16(v.z); o[3] = to_bf16(v.w);
    ((s16x4*)d)[i] = o;
  }
}

// interleave L1/L2 rows: dst[2n]=L1[n], dst[2n+1]=L2[n]   (rows of 1024)
__global__ __launch_bounds__(256, 4)
void cvt_inter(const float* __restrict__ L1, const float* __restrict__ L2,
               short* __restrict__ d) {
  int i = blockIdx.x * 256 + threadIdx.x;      // over 2816*256 float4 slots
  if (i >= INNER * 256) return;
  int row = i >> 8, c4 = i & 255;
  float4 v1 = ((const float4*)L1)[i];
  float4 v2 = ((const float4*)L2)[i];
  s16x4 o1, o2;
  o1[0]=to_bf16(v1.x); o1[1]=to_bf16(v1.y); o1[2]=to_bf16(v1.z); o1[3]=to_bf16(v1.w);
  o2[0]=to_bf16(v2.x); o2[1]=to_bf16(v2.y); o2[2]=to_bf16(v2.z); o2[3]=to_bf16(v2.w);
  ((s16x4*)d)[(size_t)(2 * row) * 256 + c4]     = o1;
  ((s16x4*)d)[(size_t)(2 * row + 1) * 256 + c4] = o2;
}

// ---------------------------------------------------------------------------
// GEMM  C[M,N] = A[M,K] @ B[N,K]^T   (bf16 in, fp32 acc), 128x128 tile, BK=64
// MODE 0: QKV  -> out0=q[std, pre-scaled], out1=k[std], out2=v transp [b,h,d,tok]
// MODE 1: Wc   -> out0 = acc + bc[n] + x[m,n]  (fp32)
// MODE 2: MLP12 (interleaved cols u,g) -> out0 = bf16(silu(u)*g), N/2 cols
// MODE 3: L3   -> out0 = acc + h32[m,n]  (fp32)
// ---------------------------------------------------------------------------
template<int MODE>
__global__ __launch_bounds__(256, 2)
void gemm_bt(const short* __restrict__ A, const short* __restrict__ Bw,
             int M, int N, int K,
             void* __restrict__ out0, void* __restrict__ out1,
             void* __restrict__ out2,
             const float* __restrict__ aux0, const float* __restrict__ aux1)
{
  __shared__ short At[128 * 64];
  __shared__ short Bt[128 * 64];
  const int t = threadIdx.x;
  const int lane = t & 63;
  const int l15 = lane & 15, lhi = lane >> 4;
  const int w  = t >> 6;
  const int wm = (w >> 1) << 6;        // wave row offset (0/64)
  const int wn = (w & 1) << 6;         // wave col offset (0/64)
  const int tilesN = N >> 7;
  const int m0 = (blockIdx.x / tilesN) << 7;
  const int n0 = (blockIdx.x % tilesN) << 7;

  // staging: thread t loads row r=t>>3, 16B piece p=t&7; source piece is
  // pre-swizzled (p ^ (r&7)) so that swizzled ds_reads see the right data.
  const int r = t >> 3;
  const int p = t & 7;
  const int psrc = p ^ (r & 7);
  const short* Ag = A  + (size_t)(m0 + r) * K + psrc * 8;
  const short* Bg = Bw + (size_t)(n0 + r) * K + psrc * 8;

  f32x4 acc[4][4];
  const f32x4 fz = {0.f, 0.f, 0.f, 0.f};
#pragma unroll
  for (int i = 0; i < 4; i++)
#pragma unroll
    for (int j = 0; j < 4; j++) acc[i][j] = fz;

  int aoff[2][4], boff[2][4];
#pragma unroll
  for (int kk = 0; kk < 2; kk++)
#pragma unroll
    for (int mt = 0; mt < 4; mt++) {
      int ra = wm + mt * 16 + l15;
      aoff[kk][mt] = ra * 128 + ((kk * 64 + lhi * 16) ^ ((ra & 7) << 4));
      int rb = wn + mt * 16 + l15;
      boff[kk][mt] = rb * 128 + ((kk * 64 + lhi * 16) ^ ((rb & 7) << 4));
    }

  for (int k0 = 0; k0 < K; k0 += 64) {
#pragma unroll
    for (int i = 0; i < 4; i++) {
      gld16((char*)At + t * 16 + i * 4096, Ag + (size_t)i * 32 * K + k0);
      gld16((char*)Bt + t * 16 + i * 4096, Bg + (size_t)i * 32 * K + k0);
    }
    __syncthreads();                       // drains vmcnt, tile visible
#pragma unroll
    for (int kk = 0; kk < 2; kk++) {
      bf16x8 a[4], b[4];
#pragma unroll
      for (int mt = 0; mt < 4; mt++)
        a[mt] = *(const bf16x8*)((const char*)At + aoff[kk][mt]);
#pragma unroll
      for (int nt = 0; nt < 4; nt++)
        b[nt] = *(const bf16x8*)((const char*)Bt + boff[kk][nt]);
#pragma unroll
      for (int mt = 0; mt < 4; mt++)
#pragma unroll
        for (int nt = 0; nt < 4; nt++)
          acc[mt][nt] = __builtin_amdgcn_mfma_f32_16x16x32_bf16(
              a[mt], b[nt], acc[mt][nt], 0, 0, 0);
    }
    __syncthreads();                       // protect tile before restage
  }

  // epilogue: element (lane,j) of acc[mt][nt] is C[mb+j][n],
  //   mb = m0+wm+mt*16+lhi*4, n = n0+wn+nt*16+l15
#pragma unroll
  for (int mt = 0; mt < 4; mt++) {
#pragma unroll
    for (int nt = 0; nt < 4; nt++) {
      const int mb = m0 + wm + mt * 16 + lhi * 4;
      const int n  = n0 + wn + nt * 16 + l15;
      if constexpr (MODE == 0) {
        const int which = n >> 10, c = n & 1023;
        if (which == 2) {                  // V: [b,h,d,tok] transposed
          const int hh = c >> 6, dd = c & 63;
          const int bb = mb >> 11, tok = mb & 2047;
          s16x4 pk;
#pragma unroll
          for (int j = 0; j < 4; j++) pk[j] = to_bf16(acc[mt][nt][j]);
          *(s16x4*)((short*)out2 +
                    (size_t)((bb * HEADS + hh) * DK + dd) * NTOK + tok) = pk;
        } else {
          short* dst = (which == 0) ? (short*)out0 : (short*)out1;
          const float scl = (which == 0) ? QSCALE : 1.0f;
#pragma unroll
          for (int j = 0; j < 4; j++)
            dst[(size_t)(mb + j) * 1024 + c] = to_bf16(acc[mt][nt][j] * scl);
        }
      } else if constexpr (MODE == 1) {
#pragma unroll
        for (int j = 0; j < 4; j++) {
          size_t idx = (size_t)(mb + j) * 1024 + n;
          ((float*)out0)[idx] = acc[mt][nt][j] + aux1[n] + aux0[idx];
        }
      } else if constexpr (MODE == 2) {
#pragma unroll
        for (int j = 0; j < 4; j++) {
          float v0 = acc[mt][nt][j];
          float v1 = __shfl_xor(v0, 1);    // partner column (u<->g pair)
          if ((lane & 1) == 0) {
            float su = v0 / (1.f + __expf(-v0));   // silu(u)
            ((short*)out0)[(size_t)(mb + j) * INNER + (n >> 1)] =
                to_bf16(su * v1);
          }
        }
      } else {                             // MODE 3
#pragma unroll
        for (int j = 0; j < 4; j++) {
          size_t idx = (size_t)(mb + j) * 1024 + n;
          ((float*)out0)[idx] = acc[mt][nt][j] + aux0[idx];
        }
      }
    }
  }
}

// ---------------------------------------------------------------------------
// Flash attention, swapped-QK^T form: grid (64 bh, 32 qtiles), 4 waves x 16 q.
// q pre-scaled by QSCALE (exp2-domain softmax). S^T = mfma(K,Q): each lane
// owns one q-row (q=lane&15) with 16 kv values -> softmax is 15 local VALU
// ops + 2 shfls. O^T = mfma(Vt,P): accumulator q-association matches, so
// m/l/alpha are lane-uniform. P repack: v_cvt_pk_bf16 + 4x ds_write_b64.
// ---------------------------------------------------------------------------
__global__ __launch_bounds__(256, 2)
void attn_k(const short* __restrict__ qb, const short* __restrict__ kb,
            const short* __restrict__ vtb, short* __restrict__ ob)
{
  __shared__ short Kt[64 * 64];
  __shared__ short Vt[64 * 64];
  __shared__ short Pt[64 * 64];
  const int t = threadIdx.x;
  const int lane = t & 63;
  const int l15 = lane & 15, lhi = lane >> 4;
  const int w = t >> 6;
  const int bh = blockIdx.x;
  const int b = bh >> 4, h = bh & 15;
  const int q0 = blockIdx.y << 6;
  const int qrow = q0 + w * 16 + l15;          // this lane's q row

  // Q fragment (B operand), row qrow, d = kk*32 + lhi*8 .. +8
  bf16x8 aq[2];
  {
    const short* qp = qb + (size_t)(b * NTOK + qrow) * EMB + h * DK + lhi * 8;
    aq[0] = *(const bf16x8*)qp;
    aq[1] = *(const bf16x8*)(qp + 32);
  }

  f32x4 acc_o[4];                // O[q=l15][d = dt*16 + lhi*4 + j]
  const f32x4 fz = {0.f, 0.f, 0.f, 0.f};
#pragma unroll
  for (int dt = 0; dt < 4; dt++) acc_o[dt] = fz;
  float m_run = -1e30f, l_run = 0.f;

  const int r = t >> 3, p = t & 7;
  const int psrc = p ^ (r & 7);
  const short* kg = kb  + (size_t)(b * NTOK + r) * EMB + h * DK + psrc * 8;
  const short* vg = vtb + (size_t)(bh * DK + r) * NTOK + psrc * 8;

  // A-frag offsets into Kt/Vt: row = x*16 + l15, col byte = kk*64 + lhi*16
  int kvoff[4][2];
#pragma unroll
  for (int x = 0; x < 4; x++)
#pragma unroll
    for (int kk = 0; kk < 2; kk++) {
      int row = x * 16 + l15;
      kvoff[x][kk] = row * 128 + ((kk * 64 + lhi * 16) ^ ((row & 7) << 4));
    }
  // P strip: row = w*16 + l15 (this lane's q), swizzled
  const int prow = w * 16 + l15;
  int pwoff[4], proff[2];
#pragma unroll
  for (int kvt = 0; kvt < 4; kvt++)
    pwoff[kvt] = prow * 128 + ((kvt * 32 + lhi * 8) ^ ((prow & 7) << 4));
#pragma unroll
  for (int kk = 0; kk < 2; kk++)
    proff[kk] = prow * 128 + ((kk * 64 + lhi * 16) ^ ((prow & 7) << 4));

  for (int kv0 = 0; kv0 < NTOK; kv0 += 64) {
    __syncthreads();                       // previous tile fully consumed
#pragma unroll
    for (int i = 0; i < 2; i++) {
      gld16((char*)Kt + t * 16 + i * 4096, kg + (size_t)(kv0 + i * 32) * EMB);
      gld16((char*)Vt + t * 16 + i * 4096, vg + (size_t)i * 32 * NTOK + kv0);
    }
    __syncthreads();

    // S^T = K @ Q^T : s[kvt] holds S[q=l15][kv = kvt*16 + lhi*4 + j]
    f32x4 s[4];
#pragma unroll
    for (int kvt = 0; kvt < 4; kvt++) {
      s[kvt] = fz;
#pragma unroll
      for (int kk = 0; kk < 2; kk++) {
        bf16x8 ak = *(const bf16x8*)((const char*)Kt + kvoff[kvt][kk]);
        s[kvt] = __builtin_amdgcn_mfma_f32_16x16x32_bf16(ak, aq[kk], s[kvt], 0, 0, 0);
      }
    }
    // online softmax: 16 lane-local values + 2-shfl reductions (exp2 domain)
    float mx = fmaxf(fmaxf(fmaxf(s[0][0], s[0][1]), fmaxf(s[0][2], s[0][3])),
                     fmaxf(fmaxf(s[1][0], s[1][1]), fmaxf(s[1][2], s[1][3])));
    float mx2 = fmaxf(fmaxf(fmaxf(s[2][0], s[2][1]), fmaxf(s[2][2], s[2][3])),
                      fmaxf(fmaxf(s[3][0], s[3][1]), fmaxf(s[3][2], s[3][3])));
    mx = fmaxf(mx, mx2);
    mx = fmaxf(mx, __shfl_xor(mx, 16));
    mx = fmaxf(mx, __shfl_xor(mx, 32));
    const float mnew = fmaxf(m_run, mx);
    const float alpha = exp2f(m_run - mnew);
    m_run = mnew;
    float sum = 0.f;
#pragma unroll
    for (int kvt = 0; kvt < 4; kvt++)
#pragma unroll
      for (int j = 0; j < 4; j++) {
        float pe = exp2f(s[kvt][j] - mnew);
        s[kvt][j] = pe;
        sum += pe;
      }
    sum += __shfl_xor(sum, 16);
    sum += __shfl_xor(sum, 32);
    l_run = l_run * alpha + sum;
#pragma unroll
    for (int dt = 0; dt < 4; dt++)
#pragma unroll
      for (int j = 0; j < 4; j++) acc_o[dt][j] *= alpha;   // alpha lane-uniform

    // pack P -> Pt (bf16, swizzled): lane writes its q-row, kv contiguous 4s
#pragma unroll
    for (int kvt = 0; kvt < 4; kvt++) {
      uint2 uu;
      uu.x = cvt_pk_bf16(s[kvt][0], s[kvt][1]);
      uu.y = cvt_pk_bf16(s[kvt][2], s[kvt][3]);
      *(uint2*)((char*)Pt + pwoff[kvt]) = uu;
    }
    // B-frag read back (same wave; compiler inserts lgkmcnt)
    bf16x8 pb[2];
#pragma unroll
    for (int kk = 0; kk < 2; kk++)
      pb[kk] = *(const bf16x8*)((const char*)Pt + proff[kk]);
    // O^T += Vt @ P^T
#pragma unroll
    for (int dt = 0; dt < 4; dt++)
#pragma unroll
      for (int kk = 0; kk < 2; kk++) {
        bf16x8 av = *(const bf16x8*)((const char*)Vt + kvoff[dt][kk]);
        acc_o[dt] = __builtin_amdgcn_mfma_f32_16x16x32_bf16(av, pb[kk], acc_o[dt], 0, 0, 0);
      }
  }

  const float inv = 1.f / l_run;
  short* op = ob + (size_t)(b * NTOK + qrow) * EMB + h * DK;
#pragma unroll
  for (int dt = 0; dt < 4; dt++) {
    s16x4 pk;
#pragma unroll
    for (int j = 0; j < 4; j++) pk[j] = to_bf16(acc_o[dt][j] * inv);
    *(s16x4*)(op + dt * 16 + lhi * 4) = pk;
  }
}

// ---------------------------------------------------------------------------
// RMSNorm over rows of 1024 fp32. WB: also emit bf16 copy.
// ---------------------------------------------------------------------------
template<bool WB>
__global__ __launch_bounds__(256, 4)
void rmsnorm_k(const float* __restrict__ in, const float* __restrict__ gw,
               float* __restrict__ of, short* __restrict__ ob)
{
  const int row = blockIdx.x;
  const int t = threadIdx.x;
  const float4 v = ((const float4*)(in + (size_t)row * EMB))[t];
  float ss = v.x * v.x + v.y * v.y + v.z * v.z + v.w * v.w;
#pragma unroll
  for (int off = 1; off < 64; off <<= 1) ss += __shfl_xor(ss, off);
  __shared__ float red[4];
  if ((t & 63) == 0) red[t >> 6] = ss;
  __syncthreads();
  float tot = red[0] + red[1] + red[2] + red[3];
  const float rinv = rsqrtf(tot * (1.f / EMB) + 1e-6f);
  const float4 g4 = ((const float4*)gw)[t];
  float4 o;
  o.x = v.x * rinv * g4.x; o.y = v.y * rinv * g4.y;
  o.z = v.z * rinv * g4.z; o.w = v.w * rinv * g4.w;
  ((float4*)(of + (size_t)row * EMB))[t] = o;
  if (WB) {
    s16x4 pk;
    pk[0] = to_bf16(o.x); pk[1] = to_bf16(o.y);
    pk[2] = to_bf16(o.z); pk[3] = to_bf16(o.w);
    ((s16x4*)(ob + (size_t)row * EMB))[t] = pk;
  }
}

// ---------------------------------------------------------------------------
extern "C" void kernel_launch(void* const* d_in, const int* in_sizes, int n_in,
                              void* d_out, int out_size, void* d_ws, size_t ws_size,
                              hipStream_t stream)
{
  const float* x  = (const float*)d_in[0];
  const float* Wq = (const float*)d_in[1];
  const float* Wk = (const float*)d_in[2];
  const float* Wv = (const float*)d_in[3];
  const float* Wc = (const float*)d_in[4];
  const float* bc = (const float*)d_in[5];
  const float* g1 = (const float*)d_in[6];
  const float* g2 = (const float*)d_in[7];
  const float* L1 = (const float*)d_in[8];
  const float* L2 = (const float*)d_in[9];
  const float* L3 = (const float*)d_in[10];
  float* out = (float*)d_out;

  char* ws = (char*)d_ws;
  size_t o = 0;
  auto take = [&](size_t bytes) -> char* {
    char* pp = ws + o;
    o += (bytes + 255) & ~(size_t)255;
    return pp;
  };
  short* xb   = (short*)take((size_t)MROWS * EMB * 2);
  short* wqkv = (short*)take((size_t)3072 * 1024 * 2);
  short* wcb  = (short*)take((size_t)1024 * 1024 * 2);
  short* l12  = (short*)take((size_t)5632 * 1024 * 2);
  short* l3b  = (short*)take((size_t)1024 * 2816 * 2);
  short* q    = (short*)take((size_t)MROWS * EMB * 2);
  short* k    = (short*)take((size_t)MROWS * EMB * 2);
  short* v    = (short*)take((size_t)MROWS * EMB * 2);
  short* attn = (short*)take((size_t)MROWS * EMB * 2);
  float* t1   = (float*)take((size_t)MROWS * EMB * 4);
  float* h32  = (float*)take((size_t)MROWS * EMB * 4);
  short* hb   = (short*)take((size_t)MROWS * EMB * 2);
  short* gated = q;   // reuse q/k/v region (dead after attention)
  float* t2    = t1;  // reuse t1 (dead after norm1)

  // conversions
  cvtk<<<MROWS * EMB / 4 / 256, 256, 0, stream>>>(x, xb, MROWS * EMB / 4);
  cvtk<<<1024 * 1024 / 4 / 256, 256, 0, stream>>>(Wq, wqkv, 1024 * 1024 / 4);
  cvtk<<<1024 * 1024 / 4 / 256, 256, 0, stream>>>(Wk, wqkv + 1024 * 1024, 1024 * 1024 / 4);
  cvtk<<<1024 * 1024 / 4 / 256, 256, 0, stream>>>(Wv, wqkv + 2 * 1024 * 1024, 1024 * 1024 / 4);
  cvtk<<<1024 * 1024 / 4 / 256, 256, 0, stream>>>(Wc, wcb, 1024 * 1024 / 4);
  cvt_inter<<<INNER, 256, 0, stream>>>(L1, L2, l12);
  cvtk<<<1024 * 2816 / 4 / 256, 256, 0, stream>>>(L3, l3b, 1024 * 2816 / 4);

  // QKV projection (N = 3072 = q|k|v); q output pre-scaled by QSCALE
  gemm_bt<0><<<64 * 24, 256, 0, stream>>>(xb, wqkv, MROWS, 3072, 1024,
                                          q, k, v, nullptr, nullptr);
  // attention
  attn_k<<<dim3(64, 32), 256, 0, stream>>>(q, k, v, attn);
  // Wc projection + bias + residual -> t1 (fp32)
  gemm_bt<1><<<64 * 8, 256, 0, stream>>>(attn, wcb, MROWS, 1024, 1024,
                                         t1, nullptr, nullptr, x, bc);
  // h = rmsnorm(t1, g1): fp32 + bf16 copies
  rmsnorm_k<true><<<MROWS, 256, 0, stream>>>(t1, g1, h32, hb);
  // gated MLP up: interleaved u,g columns, fused silu-gate -> gated (bf16)
  gemm_bt<2><<<64 * 44, 256, 0, stream>>>(hb, l12, MROWS, 5632, 1024,
                                          gated, nullptr, nullptr, nullptr, nullptr);
  // down proj + residual -> t2 (fp32)
  gemm_bt<3><<<64 * 8, 256, 0, stream>>>(gated, l3b, MROWS, 1024, 2816,
                                         t2, nullptr, nullptr, h32, nullptr);
  // final norm -> d_out
  rmsnorm_k<false><<<MROWS, 256, 0, stream>>>(t2, g2, out, nullptr);
}

// Round 3
// 442.298 us; speedup vs baseline: 1.2385x; 1.0384x over previous
//
#include <hip/hip_runtime.h>
#include <hip/hip_bf16.h>

// ---------------------------------------------------------------------------
// EncoderLayer on MI355X (gfx950), bf16 MFMA pipeline.
//   x[4,2048,1024] -> QKV proj -> MHA (flash, online softmax) -> Wc+bias+res
//   -> RMSNorm -> gated MLP (silu(h@L1.T)*(h@L2.T))@L3.T + res -> RMSNorm
// ---------------------------------------------------------------------------

#define EMB   1024
#define HEADS 16
#define DK    64
#define INNER 2816
#define BATCH 4
#define NTOK  2048
#define MROWS (BATCH * NTOK)   // 8192

// q pre-scale: 1/sqrt(64) * log2(e)  (softmax done in exp2 domain)
#define QSCALE 0.18033688011112042f

typedef short bf16x8 __attribute__((ext_vector_type(8)));
typedef short s16x4  __attribute__((ext_vector_type(4)));
typedef float f32x4  __attribute__((ext_vector_type(4)));

typedef const void __attribute__((address_space(1)))* gas_cvp;
typedef void       __attribute__((address_space(3)))* las_vp;

__device__ __forceinline__ short to_bf16(float f) {
  union { float f; unsigned u; } x; x.f = f;
  unsigned r = x.u + 0x7FFFu + ((x.u >> 16) & 1u);   // RNE
  return (short)(r >> 16);
}

// packed f32x2 -> bf16x2 (low = a, high = b)
__device__ __forceinline__ unsigned cvt_pk_bf16(float a, float b) {
  unsigned r;
  asm("v_cvt_pk_bf16_f32 %0, %1, %2" : "=v"(r) : "v"(a), "v"(b));
  return r;
}

// async global->LDS, 16B per lane; LDS dest must be linear (base + lane*16)
__device__ __forceinline__ void gld16(void* lds, const void* g) {
  __builtin_amdgcn_global_load_lds((gas_cvp)g, (las_vp)lds, 16, 0, 0);
}

// ---------------------------------------------------------------------------
// f32 -> bf16 conversion (vectorized)
// ---------------------------------------------------------------------------
__global__ __launch_bounds__(256, 4)
void cvtk(const float* __restrict__ s, short* __restrict__ d, int n4) {
  int i = blockIdx.x * 256 + threadIdx.x;
  if (i < n4) {
    float4 v = ((const float4*)s)[i];
    s16x4 o;
    o[0] = to_bf16(v.x); o[1] = to_bf16(v.y);
    o[2] = to_bf16(v.z); o[3] = to_bf16(v.w);
    ((s16x4*)d)[i] = o;
  }
}

// interleave L1/L2 rows: dst[2n]=L1[n], dst[2n+1]=L2[n]   (rows of 1024)
__global__ __launch_bounds__(256, 4)
void cvt_inter(const float* __restrict__ L1, const float* __restrict__ L2,
               short* __restrict__ d) {
  int i = blockIdx.x * 256 + threadIdx.x;      // over 2816*256 float4 slots
  if (i >= INNER * 256) return;
  int row = i >> 8, c4 = i & 255;
  float4 v1 = ((const float4*)L1)[i];
  float4 v2 = ((const float4*)L2)[i];
  s16x4 o1, o2;
  o1[0]=to_bf16(v1.x); o1[1]=to_bf16(v1.y); o1[2]=to_bf16(v1.z); o1[3]=to_bf16(v1.w);
  o2[0]=to_bf16(v2.x); o2[1]=to_bf16(v2.y); o2[2]=to_bf16(v2.z); o2[3]=to_bf16(v2.w);
  ((s16x4*)d)[(size_t)(2 * row) * 256 + c4]     = o1;
  ((s16x4*)d)[(size_t)(2 * row + 1) * 256 + c4] = o2;
}

// ---------------------------------------------------------------------------
// GEMM  C[M,N] = A[M,K] @ B[N,K]^T   (bf16 in, fp32 acc), 128x128 tile, BK=64
// MODE 0: QKV  -> out0=q[std, pre-scaled], out1=k[std], out2=v transp [b,h,d,tok]
// MODE 1: Wc   -> out0 = acc + bc[n] + x[m,n]  (fp32)
// MODE 2: MLP12 (interleaved cols u,g) -> out0 = bf16(silu(u)*g), N/2 cols
// MODE 3: L3   -> out0 = acc + h32[m,n]  (fp32)
// ---------------------------------------------------------------------------
template<int MODE>
__global__ __launch_bounds__(256, 2)
void gemm_bt(const short* __restrict__ A, const short* __restrict__ Bw,
             int M, int N, int K,
             void* __restrict__ out0, void* __restrict__ out1,
             void* __restrict__ out2,
             const float* __restrict__ aux0, const float* __restrict__ aux1)
{
  __shared__ short At[128 * 64];
  __shared__ short Bt[128 * 64];
  const int t = threadIdx.x;
  const int lane = t & 63;
  const int l15 = lane & 15, lhi = lane >> 4;
  const int w  = t >> 6;
  const int wm = (w >> 1) << 6;        // wave row offset (0/64)
  const int wn = (w & 1) << 6;         // wave col offset (0/64)
  const int tilesN = N >> 7;
  const int m0 = (blockIdx.x / tilesN) << 7;
  const int n0 = (blockIdx.x % tilesN) << 7;

  // staging: thread t loads row r=t>>3, 16B piece p=t&7; source piece is
  // pre-swizzled (p ^ (r&7)) so that swizzled ds_reads see the right data.
  const int r = t >> 3;
  const int p = t & 7;
  const int psrc = p ^ (r & 7);
  const short* Ag = A  + (size_t)(m0 + r) * K + psrc * 8;
  const short* Bg = Bw + (size_t)(n0 + r) * K + psrc * 8;

  f32x4 acc[4][4];
  const f32x4 fz = {0.f, 0.f, 0.f, 0.f};
#pragma unroll
  for (int i = 0; i < 4; i++)
#pragma unroll
    for (int j = 0; j < 4; j++) acc[i][j] = fz;

  int aoff[2][4], boff[2][4];
#pragma unroll
  for (int kk = 0; kk < 2; kk++)
#pragma unroll
    for (int mt = 0; mt < 4; mt++) {
      int ra = wm + mt * 16 + l15;
      aoff[kk][mt] = ra * 128 + ((kk * 64 + lhi * 16) ^ ((ra & 7) << 4));
      int rb = wn + mt * 16 + l15;
      boff[kk][mt] = rb * 128 + ((kk * 64 + lhi * 16) ^ ((rb & 7) << 4));
    }

  for (int k0 = 0; k0 < K; k0 += 64) {
#pragma unroll
    for (int i = 0; i < 4; i++) {
      gld16((char*)At + t * 16 + i * 4096, Ag + (size_t)i * 32 * K + k0);
      gld16((char*)Bt + t * 16 + i * 4096, Bg + (size_t)i * 32 * K + k0);
    }
    __syncthreads();                       // drains vmcnt, tile visible
#pragma unroll
    for (int kk = 0; kk < 2; kk++) {
      bf16x8 a[4], b[4];
#pragma unroll
      for (int mt = 0; mt < 4; mt++)
        a[mt] = *(const bf16x8*)((const char*)At + aoff[kk][mt]);
#pragma unroll
      for (int nt = 0; nt < 4; nt++)
        b[nt] = *(const bf16x8*)((const char*)Bt + boff[kk][nt]);
#pragma unroll
      for (int mt = 0; mt < 4; mt++)
#pragma unroll
        for (int nt = 0; nt < 4; nt++)
          acc[mt][nt] = __builtin_amdgcn_mfma_f32_16x16x32_bf16(
              a[mt], b[nt], acc[mt][nt], 0, 0, 0);
    }
    __syncthreads();                       // protect tile before restage
  }

  // epilogue: element (lane,j) of acc[mt][nt] is C[mb+j][n],
  //   mb = m0+wm+mt*16+lhi*4, n = n0+wn+nt*16+l15
#pragma unroll
  for (int mt = 0; mt < 4; mt++) {
#pragma unroll
    for (int nt = 0; nt < 4; nt++) {
      const int mb = m0 + wm + mt * 16 + lhi * 4;
      const int n  = n0 + wn + nt * 16 + l15;
      if constexpr (MODE == 0) {
        const int which = n >> 10, c = n & 1023;
        if (which == 2) {                  // V: [b,h,d,tok] transposed
          const int hh = c >> 6, dd = c & 63;
          const int bb = mb >> 11, tok = mb & 2047;
          s16x4 pk;
#pragma unroll
          for (int j = 0; j < 4; j++) pk[j] = to_bf16(acc[mt][nt][j]);
          *(s16x4*)((short*)out2 +
                    (size_t)((bb * HEADS + hh) * DK + dd) * NTOK + tok) = pk;
        } else {
          short* dst = (which == 0) ? (short*)out0 : (short*)out1;
          const float scl = (which == 0) ? QSCALE : 1.0f;
#pragma unroll
          for (int j = 0; j < 4; j++)
            dst[(size_t)(mb + j) * 1024 + c] = to_bf16(acc[mt][nt][j] * scl);
        }
      } else if constexpr (MODE == 1) {
#pragma unroll
        for (int j = 0; j < 4; j++) {
          size_t idx = (size_t)(mb + j) * 1024 + n;
          ((float*)out0)[idx] = acc[mt][nt][j] + aux1[n] + aux0[idx];
        }
      } else if constexpr (MODE == 2) {
#pragma unroll
        for (int j = 0; j < 4; j++) {
          float v0 = acc[mt][nt][j];
          float v1 = __shfl_xor(v0, 1);    // partner column (u<->g pair)
          if ((lane & 1) == 0) {
            float su = v0 / (1.f + __expf(-v0));   // silu(u)
            ((short*)out0)[(size_t)(mb + j) * INNER + (n >> 1)] =
                to_bf16(su * v1);
          }
        }
      } else {                             // MODE 3
#pragma unroll
        for (int j = 0; j < 4; j++) {
          size_t idx = (size_t)(mb + j) * 1024 + n;
          ((float*)out0)[idx] = acc[mt][nt][j] + aux0[idx];
        }
      }
    }
  }
}

// ---------------------------------------------------------------------------
// Flash attention, swapped-QK^T, 2 q-sets/wave, double-buffered K/V.
// grid (64 bh, 16): block = 4 waves x 32 q rows (2 sets of 16). KV tile 64.
// q pre-scaled by QSCALE (exp2-domain). S^T = mfma(K,Q): lane owns q=l15 with
// 16 kv values; per-lane partial l (reduced once at end); defer-max rescale.
// K/V double-buffered via global_load_lds + counted s_waitcnt vmcnt(4).
// Pt: padded row stride 136B (conflict-free b64 writes / b128 reads).
// ---------------------------------------------------------------------------
__global__ __launch_bounds__(256, 3)
void attn_k(const short* __restrict__ qb, const short* __restrict__ kb,
            const short* __restrict__ vtb, short* __restrict__ ob)
{
  __shared__ short Kt[2][64 * 64];
  __shared__ short Vt[2][64 * 64];
  __shared__ short Pt[128 * 68];            // 128 q rows, stride 68 shorts
  const int t = threadIdx.x;
  const int lane = t & 63;
  const int l15 = lane & 15, lhi = lane >> 4;
  const int w = t >> 6;
  const int bh = blockIdx.x;
  const int b = bh >> 4, h = bh & 15;
  const int q0 = blockIdx.y << 7;            // 128 q rows per block

  // Q fragments (B operand) for the two 16-row sets
  bf16x8 aq[2][2];
#pragma unroll
  for (int s = 0; s < 2; s++) {
    const short* qp = qb + (size_t)(b * NTOK + q0 + w * 32 + s * 16 + l15) * EMB
                         + h * DK + lhi * 8;
    aq[s][0] = *(const bf16x8*)qp;
    aq[s][1] = *(const bf16x8*)(qp + 32);
  }

  f32x4 acc[2][4];                // O[q=l15][d = dt*16 + lhi*4 + j] per set
  const f32x4 fz = {0.f, 0.f, 0.f, 0.f};
#pragma unroll
  for (int s = 0; s < 2; s++)
#pragma unroll
    for (int dt = 0; dt < 4; dt++) acc[s][dt] = fz;
  float m_run[2] = {-1e30f, -1e30f};
  float l_run[2] = {0.f, 0.f};     // per-lane partial sums

  const int r = t >> 3, p = t & 7;
  const int psrc = p ^ (r & 7);
  const short* kg = kb  + (size_t)(b * NTOK + r) * EMB + h * DK + psrc * 8;
  const short* vg = vtb + (size_t)(bh * DK + r) * NTOK + psrc * 8;

  // swizzled A-frag offsets into Kt/Vt: row = x*16+l15, col = kk*64+lhi*16
  int kvoff[4][2];
#pragma unroll
  for (int x = 0; x < 4; x++)
#pragma unroll
    for (int kk = 0; kk < 2; kk++) {
      int row = x * 16 + l15;
      kvoff[x][kk] = row * 128 + ((kk * 64 + lhi * 16) ^ ((row & 7) << 4));
    }
  // Pt offsets (padded, linear)
  int pw[2][4], pr[2][2];
#pragma unroll
  for (int s = 0; s < 2; s++) {
    const int prow = w * 32 + s * 16 + l15;
#pragma unroll
    for (int kvt = 0; kvt < 4; kvt++) pw[s][kvt] = prow * 136 + kvt * 32 + lhi * 8;
#pragma unroll
    for (int kk = 0; kk < 2; kk++)   pr[s][kk]  = prow * 136 + kk * 64 + lhi * 16;
  }

  auto stage = [&](short* Kd, short* Vd, int kv0) {
    const short* ks = kg + (size_t)kv0 * EMB;
    const short* vs = vg + kv0;
    gld16(Kd + t * 8,        ks);
    gld16(Kd + t * 8 + 2048, ks + (size_t)32 * EMB);
    gld16(Vd + t * 8,        vs);
    gld16(Vd + t * 8 + 2048, vs + (size_t)32 * NTOK);
  };

  // per-set softmax + P pack (defer-max; exp2 domain)
  auto do_set = [&](f32x4 (&sv)[4], float& mr, float& lr, f32x4 (&ac)[4],
                    const int (&pwo)[4]) {
    float pm = sv[0][0];
#pragma unroll
    for (int kvt = 0; kvt < 4; kvt++)
#pragma unroll
      for (int j = 0; j < 4; j++) pm = fmaxf(pm, sv[kvt][j]);
    if (__any(pm > mr + 8.0f)) {           // rare: rescale path
      pm = fmaxf(pm, __shfl_xor(pm, 16));
      pm = fmaxf(pm, __shfl_xor(pm, 32));
      const float mnew = fmaxf(mr, pm);
      const float al = exp2f(mr - mnew);
      lr *= al;
#pragma unroll
      for (int dt = 0; dt < 4; dt++)
#pragma unroll
        for (int j = 0; j < 4; j++) ac[dt][j] *= al;
      mr = mnew;
    }
    float ls = 0.f;
#pragma unroll
    for (int kvt = 0; kvt < 4; kvt++)
#pragma unroll
      for (int j = 0; j < 4; j++) {
        float pe = exp2f(sv[kvt][j] - mr);
        sv[kvt][j] = pe;
        ls += pe;
      }
    lr += ls;
#pragma unroll
    for (int kvt = 0; kvt < 4; kvt++) {
      uint2 u;
      u.x = cvt_pk_bf16(sv[kvt][0], sv[kvt][1]);
      u.y = cvt_pk_bf16(sv[kvt][2], sv[kvt][3]);
      *(uint2*)((char*)Pt + pwo[kvt]) = u;
    }
  };

  auto compute = [&](const short* Kb_, const short* Vb_) {
    const char* Kb = (const char*)Kb_;
    const char* Vb = (const char*)Vb_;
    bf16x8 kf[4][2];
#pragma unroll
    for (int x = 0; x < 4; x++)
#pragma unroll
      for (int kk = 0; kk < 2; kk++)
        kf[x][kk] = *(const bf16x8*)(Kb + kvoff[x][kk]);
    // S^T = K @ Q^T for both sets
    f32x4 s0[4], s1[4];
    __builtin_amdgcn_s_setprio(1);
#pragma unroll
    for (int kvt = 0; kvt < 4; kvt++) {
      s0[kvt] = __builtin_amdgcn_mfma_f32_16x16x32_bf16(kf[kvt][0], aq[0][0], fz, 0, 0, 0);
      s0[kvt] = __builtin_amdgcn_mfma_f32_16x16x32_bf16(kf[kvt][1], aq[0][1], s0[kvt], 0, 0, 0);
      s1[kvt] = __builtin_amdgcn_mfma_f32_16x16x32_bf16(kf[kvt][0], aq[1][0], fz, 0, 0, 0);
      s1[kvt] = __builtin_amdgcn_mfma_f32_16x16x32_bf16(kf[kvt][1], aq[1][1], s1[kvt], 0, 0, 0);
    }
    __builtin_amdgcn_s_setprio(0);
    do_set(s0, m_run[0], l_run[0], acc[0], pw[0]);
    do_set(s1, m_run[1], l_run[1], acc[1], pw[1]);
    // V frags + P frags, then PV
    bf16x8 vf[4][2];
#pragma unroll
    for (int dt = 0; dt < 4; dt++)
#pragma unroll
      for (int kk = 0; kk < 2; kk++)
        vf[dt][kk] = *(const bf16x8*)(Vb + kvoff[dt][kk]);
    bf16x8 pb0[2], pb1[2];
#pragma unroll
    for (int kk = 0; kk < 2; kk++) {
      pb0[kk] = *(const bf16x8*)((const char*)Pt + pr[0][kk]);
      pb1[kk] = *(const bf16x8*)((const char*)Pt + pr[1][kk]);
    }
    __builtin_amdgcn_s_setprio(1);
#pragma unroll
    for (int dt = 0; dt < 4; dt++) {
#pragma unroll
      for (int kk = 0; kk < 2; kk++)
        acc[0][dt] = __builtin_amdgcn_mfma_f32_16x16x32_bf16(vf[dt][kk], pb0[kk], acc[0][dt], 0, 0, 0);
#pragma unroll
      for (int kk = 0; kk < 2; kk++)
        acc[1][dt] = __builtin_amdgcn_mfma_f32_16x16x32_bf16(vf[dt][kk], pb1[kk], acc[1][dt], 0, 0, 0);
    }
    __builtin_amdgcn_s_setprio(0);
  };

  // -------- main loop: 32 KV tiles, double-buffered, counted vmcnt --------
  stage(Kt[0], Vt[0], 0);
  for (int it = 0; it < 32; it += 2) {
    // phase A: compute buf0, prefetch tile it+1 into buf1
    stage(Kt[1], Vt[1], (it + 1) * 64);
    asm volatile("s_waitcnt vmcnt(4)" ::: "memory");
    __builtin_amdgcn_s_barrier();
    compute(Kt[0], Vt[0]);
    __builtin_amdgcn_s_barrier();
    // phase B: compute buf1, prefetch tile it+2 into buf0
    if (it + 2 < 32) {
      stage(Kt[0], Vt[0], (it + 2) * 64);
      asm volatile("s_waitcnt vmcnt(4)" ::: "memory");
    } else {
      asm volatile("s_waitcnt vmcnt(0)" ::: "memory");
    }
    __builtin_amdgcn_s_barrier();
    compute(Kt[1], Vt[1]);
    __builtin_amdgcn_s_barrier();
  }

  // epilogue: reduce per-lane l across lhi, normalize, store
#pragma unroll
  for (int s = 0; s < 2; s++) {
    float lt = l_run[s];
    lt += __shfl_xor(lt, 16);
    lt += __shfl_xor(lt, 32);
    const float inv = 1.f / lt;
    short* op = ob + (size_t)(b * NTOK + q0 + w * 32 + s * 16 + l15) * EMB + h * DK;
#pragma unroll
    for (int dt = 0; dt < 4; dt++) {
      s16x4 pk;
#pragma unroll
      for (int j = 0; j < 4; j++) pk[j] = to_bf16(acc[s][dt][j] * inv);
      *(s16x4*)(op + dt * 16 + lhi * 4) = pk;
    }
  }
}

// ---------------------------------------------------------------------------
// RMSNorm over rows of 1024 fp32. WB: also emit bf16 copy.
// ---------------------------------------------------------------------------
template<bool WB>
__global__ __launch_bounds__(256, 4)
void rmsnorm_k(const float* __restrict__ in, const float* __restrict__ gw,
               float* __restrict__ of, short* __restrict__ ob)
{
  const int row = blockIdx.x;
  const int t = threadIdx.x;
  const float4 v = ((const float4*)(in + (size_t)row * EMB))[t];
  float ss = v.x * v.x + v.y * v.y + v.z * v.z + v.w * v.w;
#pragma unroll
  for (int off = 1; off < 64; off <<= 1) ss += __shfl_xor(ss, off);
  __shared__ float red[4];
  if ((t & 63) == 0) red[t >> 6] = ss;
  __syncthreads();
  float tot = red[0] + red[1] + red[2] + red[3];
  const float rinv = rsqrtf(tot * (1.f / EMB) + 1e-6f);
  const float4 g4 = ((const float4*)gw)[t];
  float4 o;
  o.x = v.x * rinv * g4.x; o.y = v.y * rinv * g4.y;
  o.z = v.z * rinv * g4.z; o.w = v.w * rinv * g4.w;
  ((float4*)(of + (size_t)row * EMB))[t] = o;
  if (WB) {
    s16x4 pk;
    pk[0] = to_bf16(o.x); pk[1] = to_bf16(o.y);
    pk[2] = to_bf16(o.z); pk[3] = to_bf16(o.w);
    ((s16x4*)(ob + (size_t)row * EMB))[t] = pk;
  }
}

// ---------------------------------------------------------------------------
extern "C" void kernel_launch(void* const* d_in, const int* in_sizes, int n_in,
                              void* d_out, int out_size, void* d_ws, size_t ws_size,
                              hipStream_t stream)
{
  const float* x  = (const float*)d_in[0];
  const float* Wq = (const float*)d_in[1];
  const float* Wk = (const float*)d_in[2];
  const float* Wv = (const float*)d_in[3];
  const float* Wc = (const float*)d_in[4];
  const float* bc = (const float*)d_in[5];
  const float* g1 = (const float*)d_in[6];
  const float* g2 = (const float*)d_in[7];
  const float* L1 = (const float*)d_in[8];
  const float* L2 = (const float*)d_in[9];
  const float* L3 = (const float*)d_in[10];
  float* out = (float*)d_out;

  char* ws = (char*)d_ws;
  size_t o = 0;
  auto take = [&](size_t bytes) -> char* {
    char* pp = ws + o;
    o += (bytes + 255) & ~(size_t)255;
    return pp;
  };
  short* xb   = (short*)take((size_t)MROWS * EMB * 2);
  short* wqkv = (short*)take((size_t)3072 * 1024 * 2);
  short* wcb  = (short*)take((size_t)1024 * 1024 * 2);
  short* l12  = (short*)take((size_t)5632 * 1024 * 2);
  short* l3b  = (short*)take((size_t)1024 * 2816 * 2);
  short* q    = (short*)take((size_t)MROWS * EMB * 2);
  short* k    = (short*)take((size_t)MROWS * EMB * 2);
  short* v    = (short*)take((size_t)MROWS * EMB * 2);
  short* attn = (short*)take((size_t)MROWS * EMB * 2);
  float* t1   = (float*)take((size_t)MROWS * EMB * 4);
  float* h32  = (float*)take((size_t)MROWS * EMB * 4);
  short* hb   = (short*)take((size_t)MROWS * EMB * 2);
  short* gated = q;   // reuse q/k/v region (dead after attention)
  float* t2    = t1;  // reuse t1 (dead after norm1)

  // conversions
  cvtk<<<MROWS * EMB / 4 / 256, 256, 0, stream>>>(x, xb, MROWS * EMB / 4);
  cvtk<<<1024 * 1024 / 4 / 256, 256, 0, stream>>>(Wq, wqkv, 1024 * 1024 / 4);
  cvtk<<<1024 * 1024 / 4 / 256, 256, 0, stream>>>(Wk, wqkv + 1024 * 1024, 1024 * 1024 / 4);
  cvtk<<<1024 * 1024 / 4 / 256, 256, 0, stream>>>(Wv, wqkv + 2 * 1024 * 1024, 1024 * 1024 / 4);
  cvtk<<<1024 * 1024 / 4 / 256, 256, 0, stream>>>(Wc, wcb, 1024 * 1024 / 4);
  cvt_inter<<<INNER, 256, 0, stream>>>(L1, L2, l12);
  cvtk<<<1024 * 2816 / 4 / 256, 256, 0, stream>>>(L3, l3b, 1024 * 2816 / 4);

  // QKV projection (N = 3072 = q|k|v); q output pre-scaled by QSCALE
  gemm_bt<0><<<64 * 24, 256, 0, stream>>>(xb, wqkv, MROWS, 3072, 1024,
                                          q, k, v, nullptr, nullptr);
  // attention (128 q rows per block)
  attn_k<<<dim3(64, 16), 256, 0, stream>>>(q, k, v, attn);
  // Wc projection + bias + residual -> t1 (fp32)
  gemm_bt<1><<<64 * 8, 256, 0, stream>>>(attn, wcb, MROWS, 1024, 1024,
                                         t1, nullptr, nullptr, x, bc);
  // h = rmsnorm(t1, g1): fp32 + bf16 copies
  rmsnorm_k<true><<<MROWS, 256, 0, stream>>>(t1, g1, h32, hb);
  // gated MLP up: interleaved u,g columns, fused silu-gate -> gated (bf16)
  gemm_bt<2><<<64 * 44, 256, 0, stream>>>(hb, l12, MROWS, 5632, 1024,
                                          gated, nullptr, nullptr, nullptr, nullptr);
  // down proj + residual -> t2 (fp32)
  gemm_bt<3><<<64 * 8, 256, 0, stream>>>(gated, l3b, MROWS, 1024, 2816,
                                         t2, nullptr, nullptr, h32, nullptr);
  // final norm -> d_out
  rmsnorm_k<false><<<MROWS, 256, 0, stream>>>(t2, g2, out, nullptr);
}